// Round 14
// baseline (437.164 us; speedup 1.0000x reference)
//
#include <hip/hip_runtime.h>
#include <hip/hip_bf16.h>
#include <math.h>

#define N_NODES 100000
#define N_EDGES 1600000
#define F_IN 128
#define F_EDGE 16
#define HC 128   // HEADS*C = 4*32
#define NB_SCAN 98   // ceil(N_NODES/1024)

typedef unsigned int uint;
typedef __attribute__((ext_vector_type(8))) short short8;   // 8 bf16 (4 VGPRs)
typedef __attribute__((ext_vector_type(4))) float f32x4;    // 4 fp32

__device__ __forceinline__ float bf_lo(uint u) { return __uint_as_float(u << 16); }
__device__ __forceinline__ float bf_hi(uint u) { return __uint_as_float(u & 0xffff0000u); }
__device__ __forceinline__ uint f2bfbits(float f) {
    union { __hip_bfloat16 h; unsigned short u; } cv;
    cv.h = __float2bfloat16(f);
    return (uint)cv.u;
}
__device__ __forceinline__ uint pack_bf2(float lo, float hi) {
    return f2bfbits(lo) | (f2bfbits(hi) << 16);
}

#if defined(__has_builtin)
#if __has_builtin(__builtin_amdgcn_fdot2_f32_bf16)
#define HAVE_DOT2_BF16 1
#endif
#endif

#ifdef HAVE_DOT2_BF16
typedef __attribute__((ext_vector_type(2))) __bf16 bf16x2_t;
__device__ __forceinline__ float dot2bf(uint a, uint b, float c) {
    return __builtin_amdgcn_fdot2_f32_bf16(
        __builtin_bit_cast(bf16x2_t, a), __builtin_bit_cast(bf16x2_t, b), c, false);
}
#else
__device__ __forceinline__ float dot2bf(uint a, uint b, float c) {
    return fmaf(bf_lo(a), bf_lo(b), fmaf(bf_hi(a), bf_hi(b), c));
}
#endif

// DPP-based butterfly add over the 16-lane row (sum-invariant permutations).
template<int CTRL>
__device__ __forceinline__ float dpp_addf(float v) {
    int s = __builtin_amdgcn_update_dpp(0, __float_as_int(v), CTRL, 0xF, 0xF, false);
    return v + __int_as_float(s);
}
__device__ __forceinline__ float row16_sum(float p) {
    p = dpp_addf<0xB1>(p);
    p = dpp_addf<0x4E>(p);
    p = dpp_addf<0x141>(p);
    p = dpp_addf<0x140>(p);
    return p;
}

// ---------------------------------------------------------------------------
__global__ void count_kernel(const int* __restrict__ dst, int* __restrict__ deg)
{
    int e = blockIdx.x * blockDim.x + threadIdx.x;
    if (e < N_EDGES) atomicAdd(&deg[dst[e]], 1);
}

// ---------------------------------------------------------------------------
// MFMA projection reading x/W as f32 DIRECTLY (in-register bf16 pack):
// xl = bf16(x@Wl^T+bl), xr = bf16(x@Wr^T+br).
// Block = 64 rows x 256 out-channels; 4 waves; 64 mfma 16x16x32 each.
// Per (row,kk) the 4 kg-lanes read a contiguous 128B span -> line-coalesced.
// Removes the xb4/wb4 staging pass (-51MB HBM round-trip vs R13).
// ---------------------------------------------------------------------------
__global__ __launch_bounds__(256) void proj_mfma_kernel(
    const float* __restrict__ x,
    const float* __restrict__ Wl, const float* __restrict__ Wr,
    const float* __restrict__ bl, const float* __restrict__ br,
    unsigned short* __restrict__ xlb, unsigned short* __restrict__ xrb)
{
    int w  = threadIdx.x >> 6;
    int l  = threadIdx.x & 63;
    int rl = l & 15;           // A-row / B-col / D-col within tile
    int kg = l >> 4;           // k-group; D-row base = 4*kg
    int row0 = blockIdx.x * 64;
    int col0 = w * 64;

    f32x4 acc[4][4];
    #pragma unroll
    for (int i = 0; i < 4; ++i)
        #pragma unroll
        for (int j = 0; j < 4; ++j) acc[i][j] = (f32x4){0.f, 0.f, 0.f, 0.f};

    #pragma unroll
    for (int kk = 0; kk < 4; ++kk) {
        short8 a[4];
        #pragma unroll
        for (int rt = 0; rt < 4; ++rt) {
            int row = row0 + rt * 16 + rl;
            if (row >= N_NODES) row = N_NODES - 1;   // clamp; store guarded
            const float4* xp = (const float4*)(x + (size_t)row * F_IN + kk * 32 + kg * 8);
            float4 v0 = xp[0], v1 = xp[1];
            uint4 o;
            o.x = pack_bf2(v0.x, v0.y); o.y = pack_bf2(v0.z, v0.w);
            o.z = pack_bf2(v1.x, v1.y); o.w = pack_bf2(v1.z, v1.w);
            a[rt] = __builtin_bit_cast(short8, o);
        }
        #pragma unroll
        for (int ct = 0; ct < 4; ++ct) {
            int ch = col0 + ct * 16 + rl;            // 0..255
            const float* W = (ch < HC) ? Wl : Wr;
            const float4* wp = (const float4*)(W + (size_t)(ch & 127) * F_IN + kk * 32 + kg * 8);
            float4 v0 = wp[0], v1 = wp[1];
            uint4 o;
            o.x = pack_bf2(v0.x, v0.y); o.y = pack_bf2(v0.z, v0.w);
            o.z = pack_bf2(v1.x, v1.y); o.w = pack_bf2(v1.z, v1.w);
            short8 b = __builtin_bit_cast(short8, o);
            #pragma unroll
            for (int rt = 0; rt < 4; ++rt)
                acc[rt][ct] = __builtin_amdgcn_mfma_f32_16x16x32_bf16(
                    a[rt], b, acc[rt][ct], 0, 0, 0);
        }
    }

    #pragma unroll
    for (int ct = 0; ct < 4; ++ct) {
        int ch = col0 + ct * 16 + rl;
        float bs = (ch < HC) ? bl[ch] : br[ch - HC];
        unsigned short* outp = (ch < HC) ? xlb : xrb;
        uint chm = (uint)(ch & 127);
        #pragma unroll
        for (int rt = 0; rt < 4; ++rt) {
            #pragma unroll
            for (int r = 0; r < 4; ++r) {
                int row = row0 + rt * 16 + 4 * kg + r;
                if (row < N_NODES)
                    outp[(uint)row * 128u + chm] =
                        (unsigned short)f2bfbits(acc[rt][ct][r] + bs);
            }
        }
    }
}

// ---------------------------------------------------------------------------
// 3-phase scan
__global__ __launch_bounds__(1024) void scan1_kernel(
    const int* __restrict__ deg, int* __restrict__ row_start, int* __restrict__ bsum)
{
    __shared__ int sm[1024];
    int t = threadIdx.x;
    int i = blockIdx.x * 1024 + t;
    int v = (i < N_NODES) ? deg[i] : 0;
    sm[t] = v;
    __syncthreads();
    for (int off = 1; off < 1024; off <<= 1) {
        int o = (t >= off) ? sm[t - off] : 0;
        __syncthreads();
        sm[t] += o;
        __syncthreads();
    }
    if (i < N_NODES) row_start[i] = sm[t] - v;
    if (t == 1023) bsum[blockIdx.x] = sm[1023];
}

__global__ __launch_bounds__(128) void scan2_kernel(
    const int* __restrict__ bsum, int* __restrict__ boff)
{
    __shared__ int sm[128];
    int t = threadIdx.x;
    int v = (t < NB_SCAN) ? bsum[t] : 0;
    sm[t] = v;
    __syncthreads();
    for (int off = 1; off < 128; off <<= 1) {
        int o = (t >= off) ? sm[t - off] : 0;
        __syncthreads();
        sm[t] += o;
        __syncthreads();
    }
    if (t < NB_SCAN) boff[t] = sm[t] - v;
}

__global__ __launch_bounds__(1024) void scan3_kernel(
    int* __restrict__ row_start, const int* __restrict__ boff, int* __restrict__ cursor)
{
    int i = blockIdx.x * 1024 + threadIdx.x;
    if (i < N_NODES) {
        int r = row_start[i] + boff[blockIdx.x];
        row_start[i] = r;
        cursor[i] = r;
    }
    if (i == 0) row_start[N_NODES] = N_EDGES;
}

// scatter: CSR-ordered src (4B) + CSR-ordered bf16 edge_attr (32B) per edge
__global__ void scatter_kernel(
    const int* __restrict__ src, const int* __restrict__ dst,
    const float* __restrict__ edge_attr,
    int* __restrict__ cursor, int* __restrict__ csr_src, uint4* __restrict__ csr_ea)
{
    int e = blockIdx.x * blockDim.x + threadIdx.x;
    if (e < N_EDGES) {
        int d   = dst[e];
        int pos = atomicAdd(&cursor[d], 1);
        csr_src[pos] = src[e];
        const float4* ep = (const float4*)(edge_attr + (size_t)e * F_EDGE);
        float4 t0 = ep[0], t1 = ep[1], t2 = ep[2], t3 = ep[3];
        uint4 a, b;
        a.x = pack_bf2(t0.x, t0.y);  a.y = pack_bf2(t0.z, t0.w);
        a.z = pack_bf2(t1.x, t1.y);  a.w = pack_bf2(t1.z, t1.w);
        b.x = pack_bf2(t2.x, t2.y);  b.y = pack_bf2(t2.z, t2.w);
        b.z = pack_bf2(t3.x, t3.y);  b.w = pack_bf2(t3.z, t3.w);
        csr_ea[2 * (size_t)pos]     = a;
        csr_ea[2 * (size_t)pos + 1] = b;
    }
}

// ---------------------------------------------------------------------------
// ONE WAVE = ONE BLOCK (64 threads, grid = N_NODES). Lane owns channels
// 2l,2l+1 (head = l>>4). NO LDS. DPP head reduce; exp2 with pre-scaled att.
// __launch_bounds__(64,6): hint ladder measured on this body:
//   4 -> 44 VGPR no spill | 6 -> 40 no spill | 7 -> 36 MILD SPILL (+340MB)
//   8 -> 32 CATASTROPHIC (+1.5GB). The kernel needs ~40 VGPR; 6 is the
// highest spill-free hint. DO NOT raise it.
// ---------------------------------------------------------------------------
__global__ __launch_bounds__(64, 6) void node_kernel(
    const float* __restrict__ x, const unsigned short* __restrict__ xlb,
    const unsigned short* __restrict__ xrb,
    const int* __restrict__ row_start, const int* __restrict__ csr_src,
    const uint* __restrict__ ea_w,
    const float* __restrict__ We, const float* __restrict__ att,
    const float* __restrict__ bias, float* __restrict__ out)
{
    uint lane = threadIdx.x & 63;
    int node = blockIdx.x;

    int c0 = 2 * lane, c1 = 2 * lane + 1;

    uint wpA[8], wpB[8];
    {
        const float4* wa = (const float4*)(We + (size_t)c0 * F_EDGE);
        const float4* wb = (const float4*)(We + (size_t)c1 * F_EDGE);
        #pragma unroll
        for (int q = 0; q < 4; ++q) {
            float4 va = wa[q], vb = wb[q];
            wpA[2*q]   = pack_bf2(va.x, va.y);
            wpA[2*q+1] = pack_bf2(va.z, va.w);
            wpB[2*q]   = pack_bf2(vb.x, vb.y);
            wpB[2*q+1] = pack_bf2(vb.z, vb.w);
        }
    }
    const float LOG2E = 1.44269504088896340736f;
    float attA = att[c0], attB = att[c1];
    float attA6 = 0.6f * attA * LOG2E, attA4 = 0.4f * attA * LOG2E;
    float attB6 = 0.6f * attB * LOG2E, attB4 = 0.4f * attB * LOG2E;
    uint xru = ((const uint*)xrb)[(uint)node * 64u + lane];
    float xrA = bf_lo(xru), xrB = bf_hi(xru);

    int rs = row_start[node], re = row_start[node + 1];
    int deg = re - rs;

    const uint* xl32 = (const uint*)xlb;

    float d = 0.f, accA = 0.f, accB = 0.f;
    float eAs = 0.f, eBs = 0.f;   // accumulate (xr + e) per edge

    auto edge_core = [&](float eA, float eB, uint g) {
        eAs += eA; eBs += eB;
        float xlA = bf_lo(g), xlB = bf_hi(g);
        float sA = eA + xlA;
        float sB = eB + xlB;
        float p = attA6 * sA;
        p = fmaf(attA4, fabsf(sA), p);
        p = fmaf(attB6, sB, p);
        p = fmaf(attB4, fabsf(sB), p);
        p = row16_sum(p);
        float w = exp2f(p);
        d += w;
        accA = fmaf(w, xlA, accA);
        accB = fmaf(w, xlB, accB);
    };

    int ngrp = deg >> 3;
    if (ngrp > 0) {
        int sA8 = 0, sB8 = 0;
        uint wA = 0, wB = 0;
        uint gA[8], gB[8];

        auto LOADW = [&](int jb, int& s8, uint& w) {
            s8 = csr_src[(uint)jb + (lane >> 3)];        // src of edge (lane>>3)
            w  = ea_w[(uint)jb * 8u + lane];             // 256B contiguous ea words
        };
        auto GATHER = [&](int s8, uint g[8]) {
            #pragma unroll
            for (int k = 0; k < 8; ++k) {
                uint s = (uint)__builtin_amdgcn_readlane(s8, 8 * k);  // uniform -> SGPR
                g[k] = xl32[s * 64u + lane];
            }
        };
        auto COMP = [&](uint w, const uint g[8]) {
            #pragma unroll
            for (int k = 0; k < 8; ++k) {
                float eA = xrA, eB = xrB;
                #pragma unroll
                for (int j = 0; j < 8; ++j) {
                    uint ew = (uint)__builtin_amdgcn_readlane((int)w, 8 * k + j);
                    eA = dot2bf(ew, wpA[j], eA);
                    eB = dot2bf(ew, wpB[j], eB);
                }
                edge_core(eA, eB, g[k]);
            }
        };

        LOADW(rs, sA8, wA);
        if (ngrp > 1) LOADW(rs + 8, sB8, wB);
        GATHER(sA8, gA);
        for (int gq = 0; gq < ngrp; gq += 2) {
            bool hasB = (gq + 1 < ngrp);
            if (hasB) GATHER(sB8, gB);
            int sN = 0; uint wN = 0;
            if (gq + 2 < ngrp) LOADW(rs + 8 * (gq + 2), sN, wN);
            COMP(wA, gA);
            sA8 = sN; wA = wN;
            if (hasB) {
                if (gq + 2 < ngrp) GATHER(sA8, gA);
                int sM = 0; uint wM = 0;
                if (gq + 3 < ngrp) LOADW(rs + 8 * (gq + 3), sM, wM);
                COMP(wB, gB);
                sB8 = sM; wB = wM;
            }
        }
    }
    // tail edges (deg % 8)
    for (int j = rs + (ngrp << 3); j < re; ++j) {
        uint s = (uint)csr_src[j];
        uint g = xl32[s * 64u + lane];
        const uint4* ep = (const uint4*)(ea_w + (uint)j * 8u);
        uint4 a = ep[0], b = ep[1];
        uint ea[8] = {a.x, a.y, a.z, a.w, b.x, b.y, b.z, b.w};
        float eA = xrA, eB = xrB;
        #pragma unroll
        for (int k = 0; k < 8; ++k) {
            eA = dot2bf(ea[k], wpA[k], eA);
            eB = dot2bf(ea[k], wpB[k], eB);
        }
        edge_core(eA, eB, g);
    }

    // self-loop: (xr + e_mean) = mean of accumulated (xr + e) over edges
    {
        uint g = xl32[(uint)node * 64u + lane];
        float xlA = bf_lo(g), xlB = bf_hi(g);
        float eA, eB;
        if (deg > 0) {
            float inv = 1.f / (float)deg;
            eA = eAs * inv; eB = eBs * inv;
        } else {
            eA = xrA; eB = xrB;
        }
        float sA = eA + xlA;
        float sB = eB + xlB;
        float p = attA6 * sA;
        p = fmaf(attA4, fabsf(sA), p);
        p = fmaf(attB6, sB, p);
        p = fmaf(attB4, fabsf(sB), p);
        p = row16_sum(p);
        float w = exp2f(p);
        d += w;
        accA = fmaf(w, xlA, accA);
        accB = fmaf(w, xlB, accB);
    }

    float invd = 1.f / d;
    float oA = accA * invd + bias[c0];
    float oB = accB * invd + bias[c1];
    float2 xv = *(const float2*)(x + (uint)node * HC + c0);
    float2 o;
    o.x = fmaxf(oA, 0.f) + xv.x;
    o.y = fmaxf(oB, 0.f) + xv.y;
    *(float2*)(out + (uint)node * HC + c0) = o;
}

// ---------------------------------------------------------------------------
extern "C" void kernel_launch(void* const* d_in, const int* in_sizes, int n_in,
                              void* d_out, int out_size, void* d_ws, size_t ws_size,
                              hipStream_t stream)
{
    const float* x         = (const float*)d_in[0];
    const int*   ei        = (const int*)d_in[1];
    const float* edge_attr = (const float*)d_in[2];
    const float* Wl   = (const float*)d_in[5];
    const float* bl   = (const float*)d_in[6];
    const float* Wr   = (const float*)d_in[7];
    const float* br   = (const float*)d_in[8];
    const float* We   = (const float*)d_in[9];
    const float* att  = (const float*)d_in[10];
    const float* bias = (const float*)d_in[11];
    float* out = (float*)d_out;

    const int* src = ei;
    const int* dst = ei + N_EDGES;

    char* p = (char*)d_ws;
    auto alloc = [&](size_t bytes) {
        void* r = (void*)p;
        p += (bytes + 255) & ~(size_t)255;
        return r;
    };
    unsigned short* xlb = (unsigned short*)alloc((size_t)N_NODES * HC * sizeof(unsigned short));
    unsigned short* xrb = (unsigned short*)alloc((size_t)N_NODES * HC * sizeof(unsigned short));
    int* deg        = (int*)alloc((size_t)N_NODES * sizeof(int));
    int* row_start  = (int*)alloc((size_t)(N_NODES + 1) * sizeof(int));
    int* cursor     = (int*)alloc((size_t)N_NODES * sizeof(int));
    int* csr_src    = (int*)alloc((size_t)N_EDGES * sizeof(int));
    uint4* csr_ea   = (uint4*)alloc((size_t)N_EDGES * 2 * sizeof(uint4));
    int* bsum       = (int*)alloc(256 * sizeof(int));
    int* boff       = (int*)alloc(256 * sizeof(int));

    hipMemsetAsync(deg, 0, (size_t)N_NODES * sizeof(int), stream);

    count_kernel<<<(N_EDGES + 255) / 256, 256, 0, stream>>>(dst, deg);
    proj_mfma_kernel<<<(N_NODES + 63) / 64, 256, 0, stream>>>(x, Wl, Wr, bl, br, xlb, xrb);
    scan1_kernel<<<NB_SCAN, 1024, 0, stream>>>(deg, row_start, bsum);
    scan2_kernel<<<1, 128, 0, stream>>>(bsum, boff);
    scan3_kernel<<<NB_SCAN, 1024, 0, stream>>>(row_start, boff, cursor);
    scatter_kernel<<<(N_EDGES + 255) / 256, 256, 0, stream>>>(src, dst, edge_attr, cursor, csr_src, csr_ea);
    node_kernel<<<N_NODES, 64, 0, stream>>>(
        x, xlb, xrb, row_start, csr_src, (const uint*)csr_ea, We, att, bias, out);
}

// Round 15
// 413.263 us; speedup vs baseline: 1.0578x; 1.0578x over previous
//
#include <hip/hip_runtime.h>
#include <hip/hip_bf16.h>
#include <math.h>

#define N_NODES 100000
#define N_EDGES 1600000
#define F_IN 128
#define F_EDGE 16
#define HC 128   // HEADS*C = 4*32
#define NB_SCAN 98   // ceil(N_NODES/1024)

typedef unsigned int uint;
typedef __attribute__((ext_vector_type(8))) short short8;   // 8 bf16 (4 VGPRs)
typedef __attribute__((ext_vector_type(4))) float f32x4;    // 4 fp32

__device__ __forceinline__ float bf_lo(uint u) { return __uint_as_float(u << 16); }
__device__ __forceinline__ float bf_hi(uint u) { return __uint_as_float(u & 0xffff0000u); }
__device__ __forceinline__ uint f2bfbits(float f) {
    union { __hip_bfloat16 h; unsigned short u; } cv;
    cv.h = __float2bfloat16(f);
    return (uint)cv.u;
}
__device__ __forceinline__ uint pack_bf2(float lo, float hi) {
    return f2bfbits(lo) | (f2bfbits(hi) << 16);
}

#if defined(__has_builtin)
#if __has_builtin(__builtin_amdgcn_fdot2_f32_bf16)
#define HAVE_DOT2_BF16 1
#endif
#endif

#ifdef HAVE_DOT2_BF16
typedef __attribute__((ext_vector_type(2))) __bf16 bf16x2_t;
__device__ __forceinline__ float dot2bf(uint a, uint b, float c) {
    return __builtin_amdgcn_fdot2_f32_bf16(
        __builtin_bit_cast(bf16x2_t, a), __builtin_bit_cast(bf16x2_t, b), c, false);
}
#else
__device__ __forceinline__ float dot2bf(uint a, uint b, float c) {
    return fmaf(bf_lo(a), bf_lo(b), fmaf(bf_hi(a), bf_hi(b), c));
}
#endif

// DPP-based butterfly add over the 16-lane row (sum-invariant permutations).
template<int CTRL>
__device__ __forceinline__ float dpp_addf(float v) {
    int s = __builtin_amdgcn_update_dpp(0, __float_as_int(v), CTRL, 0xF, 0xF, false);
    return v + __int_as_float(s);
}
__device__ __forceinline__ float row16_sum(float p) {
    p = dpp_addf<0xB1>(p);
    p = dpp_addf<0x4E>(p);
    p = dpp_addf<0x141>(p);
    p = dpp_addf<0x140>(p);
    return p;
}

// ---------------------------------------------------------------------------
// Fused: degree count + x f32->bf16 (xb) + W f32->bf16 (wb, [Wl rows; Wr rows])
// (R14 lesson: proj reading f32 directly is SLOWER — 4x redundant A-row reads
// across the block's waves + 16 pack-cvt VALU per fragment inside the MFMA
// loop outweigh the 51MB xb4 round-trip. Keep this staging pass.)
// ---------------------------------------------------------------------------
__global__ void cvt_count_kernel(
    const float* __restrict__ x,
    const float* __restrict__ Wl, const float* __restrict__ Wr,
    const int* __restrict__ dst, int* __restrict__ deg,
    uint4* __restrict__ xb4, uint4* __restrict__ wb4)
{
    int t = blockIdx.x * 256 + threadIdx.x;
    if (t < N_EDGES) {
        atomicAdd(&deg[dst[t]], 1);
        const float4* xp = (const float4*)x + (size_t)t * 2;
        float4 v0 = xp[0], v1 = xp[1];
        uint4 o;
        o.x = pack_bf2(v0.x, v0.y); o.y = pack_bf2(v0.z, v0.w);
        o.z = pack_bf2(v1.x, v1.y); o.w = pack_bf2(v1.z, v1.w);
        xb4[t] = o;
    }
    if (t < 4096) {   // W: 2 x 16384 f32 = 4096 threads x 8
        const float* W = (t < 2048) ? Wl : Wr;
        const float4* wp = (const float4*)W + (size_t)(t & 2047) * 2;
        float4 v0 = wp[0], v1 = wp[1];
        uint4 o;
        o.x = pack_bf2(v0.x, v0.y); o.y = pack_bf2(v0.z, v0.w);
        o.z = pack_bf2(v1.x, v1.y); o.w = pack_bf2(v1.z, v1.w);
        wb4[t] = o;
    }
}

// ---------------------------------------------------------------------------
// MFMA projection: xl = bf16(x@Wl^T+bl), xr = bf16(x@Wr^T+br).
// Block = 64 rows x 256 out-channels; 4 waves; 64 mfma 16x16x32 each.
// Fragment layout (gfx950, m89-verified C/D): A lane l -> row l&15,
// k = 8*(l>>4)+j (16B contiguous); B lane l -> col l&15, same k;
// D lane l reg r -> row 4*(l>>4)+r, col l&15.
// ---------------------------------------------------------------------------
__global__ __launch_bounds__(256) void proj_mfma_kernel(
    const uint4* __restrict__ xb4, const uint4* __restrict__ wb4,
    const float* __restrict__ bl, const float* __restrict__ br,
    unsigned short* __restrict__ xlb, unsigned short* __restrict__ xrb)
{
    int w  = threadIdx.x >> 6;
    int l  = threadIdx.x & 63;
    int rl = l & 15;
    int kg = l >> 4;
    int row0 = blockIdx.x * 64;
    int col0 = w * 64;

    f32x4 acc[4][4];
    #pragma unroll
    for (int i = 0; i < 4; ++i)
        #pragma unroll
        for (int j = 0; j < 4; ++j) acc[i][j] = (f32x4){0.f, 0.f, 0.f, 0.f};

    #pragma unroll
    for (int kk = 0; kk < 4; ++kk) {
        short8 a[4];
        #pragma unroll
        for (int rt = 0; rt < 4; ++rt) {
            int row = row0 + rt * 16 + rl;
            if (row >= N_NODES) row = N_NODES - 1;   // clamp; store guarded
            a[rt] = __builtin_bit_cast(short8, xb4[(uint)row * 16u + kk * 4 + kg]);
        }
        #pragma unroll
        for (int ct = 0; ct < 4; ++ct) {
            int ch = col0 + ct * 16 + rl;            // 0..255
            short8 b = __builtin_bit_cast(short8, wb4[(uint)ch * 16u + kk * 4 + kg]);
            #pragma unroll
            for (int rt = 0; rt < 4; ++rt)
                acc[rt][ct] = __builtin_amdgcn_mfma_f32_16x16x32_bf16(
                    a[rt], b, acc[rt][ct], 0, 0, 0);
        }
    }

    #pragma unroll
    for (int ct = 0; ct < 4; ++ct) {
        int ch = col0 + ct * 16 + rl;
        float bs = (ch < HC) ? bl[ch] : br[ch - HC];
        unsigned short* outp = (ch < HC) ? xlb : xrb;
        uint chm = (uint)(ch & 127);
        #pragma unroll
        for (int rt = 0; rt < 4; ++rt) {
            #pragma unroll
            for (int r = 0; r < 4; ++r) {
                int row = row0 + rt * 16 + 4 * kg + r;
                if (row < N_NODES)
                    outp[(uint)row * 128u + chm] =
                        (unsigned short)f2bfbits(acc[rt][ct][r] + bs);
            }
        }
    }
}

// ---------------------------------------------------------------------------
// 3-phase scan
__global__ __launch_bounds__(1024) void scan1_kernel(
    const int* __restrict__ deg, int* __restrict__ row_start, int* __restrict__ bsum)
{
    __shared__ int sm[1024];
    int t = threadIdx.x;
    int i = blockIdx.x * 1024 + t;
    int v = (i < N_NODES) ? deg[i] : 0;
    sm[t] = v;
    __syncthreads();
    for (int off = 1; off < 1024; off <<= 1) {
        int o = (t >= off) ? sm[t - off] : 0;
        __syncthreads();
        sm[t] += o;
        __syncthreads();
    }
    if (i < N_NODES) row_start[i] = sm[t] - v;
    if (t == 1023) bsum[blockIdx.x] = sm[1023];
}

__global__ __launch_bounds__(128) void scan2_kernel(
    const int* __restrict__ bsum, int* __restrict__ boff)
{
    __shared__ int sm[128];
    int t = threadIdx.x;
    int v = (t < NB_SCAN) ? bsum[t] : 0;
    sm[t] = v;
    __syncthreads();
    for (int off = 1; off < 128; off <<= 1) {
        int o = (t >= off) ? sm[t - off] : 0;
        __syncthreads();
        sm[t] += o;
        __syncthreads();
    }
    if (t < NB_SCAN) boff[t] = sm[t] - v;
}

__global__ __launch_bounds__(1024) void scan3_kernel(
    int* __restrict__ row_start, const int* __restrict__ boff, int* __restrict__ cursor)
{
    int i = blockIdx.x * 1024 + threadIdx.x;
    if (i < N_NODES) {
        int r = row_start[i] + boff[blockIdx.x];
        row_start[i] = r;
        cursor[i] = r;
    }
    if (i == 0) row_start[N_NODES] = N_EDGES;
}

// scatter: CSR-ordered src (4B) + CSR-ordered bf16 edge_attr (32B) per edge
// (measured best: direct single-pass; eid-scatter+reorder was slower, R7)
__global__ void scatter_kernel(
    const int* __restrict__ src, const int* __restrict__ dst,
    const float* __restrict__ edge_attr,
    int* __restrict__ cursor, int* __restrict__ csr_src, uint4* __restrict__ csr_ea)
{
    int e = blockIdx.x * blockDim.x + threadIdx.x;
    if (e < N_EDGES) {
        int d   = dst[e];
        int pos = atomicAdd(&cursor[d], 1);
        csr_src[pos] = src[e];
        const float4* ep = (const float4*)(edge_attr + (size_t)e * F_EDGE);
        float4 t0 = ep[0], t1 = ep[1], t2 = ep[2], t3 = ep[3];
        uint4 a, b;
        a.x = pack_bf2(t0.x, t0.y);  a.y = pack_bf2(t0.z, t0.w);
        a.z = pack_bf2(t1.x, t1.y);  a.w = pack_bf2(t1.z, t1.w);
        b.x = pack_bf2(t2.x, t2.y);  b.y = pack_bf2(t2.z, t2.w);
        b.z = pack_bf2(t3.x, t3.y);  b.w = pack_bf2(t3.z, t3.w);
        csr_ea[2 * (size_t)pos]     = a;
        csr_ea[2 * (size_t)pos + 1] = b;
    }
}

// ---------------------------------------------------------------------------
// ONE WAVE = ONE BLOCK (64 threads, grid = N_NODES). Lane owns channels
// 2l,2l+1 (head = l>>4). NO LDS. DPP head reduce; exp2 with pre-scaled att.
// __launch_bounds__(64,6): hint ladder measured on this body:
//   4 -> 44 VGPR no spill | 6 -> 40 no spill | 7 -> 36 MILD SPILL (+340MB)
//   8 -> 32 CATASTROPHIC (+1.5GB). The kernel needs ~40 VGPR; 6 is the
// highest spill-free hint. DO NOT raise it.
// ---------------------------------------------------------------------------
__global__ __launch_bounds__(64, 6) void node_kernel(
    const float* __restrict__ x, const unsigned short* __restrict__ xlb,
    const unsigned short* __restrict__ xrb,
    const int* __restrict__ row_start, const int* __restrict__ csr_src,
    const uint* __restrict__ ea_w,
    const float* __restrict__ We, const float* __restrict__ att,
    const float* __restrict__ bias, float* __restrict__ out)
{
    uint lane = threadIdx.x & 63;
    int node = blockIdx.x;

    int c0 = 2 * lane, c1 = 2 * lane + 1;

    uint wpA[8], wpB[8];
    {
        const float4* wa = (const float4*)(We + (size_t)c0 * F_EDGE);
        const float4* wb = (const float4*)(We + (size_t)c1 * F_EDGE);
        #pragma unroll
        for (int q = 0; q < 4; ++q) {
            float4 va = wa[q], vb = wb[q];
            wpA[2*q]   = pack_bf2(va.x, va.y);
            wpA[2*q+1] = pack_bf2(va.z, va.w);
            wpB[2*q]   = pack_bf2(vb.x, vb.y);
            wpB[2*q+1] = pack_bf2(vb.z, vb.w);
        }
    }
    const float LOG2E = 1.44269504088896340736f;
    float attA = att[c0], attB = att[c1];
    float attA6 = 0.6f * attA * LOG2E, attA4 = 0.4f * attA * LOG2E;
    float attB6 = 0.6f * attB * LOG2E, attB4 = 0.4f * attB * LOG2E;
    uint xru = ((const uint*)xrb)[(uint)node * 64u + lane];
    float xrA = bf_lo(xru), xrB = bf_hi(xru);

    int rs = row_start[node], re = row_start[node + 1];
    int deg = re - rs;

    const uint* xl32 = (const uint*)xlb;

    float d = 0.f, accA = 0.f, accB = 0.f;
    float eAs = 0.f, eBs = 0.f;   // accumulate (xr + e) per edge

    auto edge_core = [&](float eA, float eB, uint g) {
        eAs += eA; eBs += eB;
        float xlA = bf_lo(g), xlB = bf_hi(g);
        float sA = eA + xlA;
        float sB = eB + xlB;
        float p = attA6 * sA;
        p = fmaf(attA4, fabsf(sA), p);
        p = fmaf(attB6, sB, p);
        p = fmaf(attB4, fabsf(sB), p);
        p = row16_sum(p);
        float w = exp2f(p);
        d += w;
        accA = fmaf(w, xlA, accA);
        accB = fmaf(w, xlB, accB);
    };

    int ngrp = deg >> 3;
    if (ngrp > 0) {
        int sA8 = 0, sB8 = 0;
        uint wA = 0, wB = 0;
        uint gA[8], gB[8];

        auto LOADW = [&](int jb, int& s8, uint& w) {
            s8 = csr_src[(uint)jb + (lane >> 3)];        // src of edge (lane>>3)
            w  = ea_w[(uint)jb * 8u + lane];             // 256B contiguous ea words
        };
        auto GATHER = [&](int s8, uint g[8]) {
            #pragma unroll
            for (int k = 0; k < 8; ++k) {
                uint s = (uint)__builtin_amdgcn_readlane(s8, 8 * k);  // uniform -> SGPR
                g[k] = xl32[s * 64u + lane];
            }
        };
        auto COMP = [&](uint w, const uint g[8]) {
            #pragma unroll
            for (int k = 0; k < 8; ++k) {
                float eA = xrA, eB = xrB;
                #pragma unroll
                for (int j = 0; j < 8; ++j) {
                    uint ew = (uint)__builtin_amdgcn_readlane((int)w, 8 * k + j);
                    eA = dot2bf(ew, wpA[j], eA);
                    eB = dot2bf(ew, wpB[j], eB);
                }
                edge_core(eA, eB, g[k]);
            }
        };

        LOADW(rs, sA8, wA);
        if (ngrp > 1) LOADW(rs + 8, sB8, wB);
        GATHER(sA8, gA);
        for (int gq = 0; gq < ngrp; gq += 2) {
            bool hasB = (gq + 1 < ngrp);
            if (hasB) GATHER(sB8, gB);
            int sN = 0; uint wN = 0;
            if (gq + 2 < ngrp) LOADW(rs + 8 * (gq + 2), sN, wN);
            COMP(wA, gA);
            sA8 = sN; wA = wN;
            if (hasB) {
                if (gq + 2 < ngrp) GATHER(sA8, gA);
                int sM = 0; uint wM = 0;
                if (gq + 3 < ngrp) LOADW(rs + 8 * (gq + 3), sM, wM);
                COMP(wB, gB);
                sB8 = sM; wB = wM;
            }
        }
    }
    // tail edges (deg % 8)
    for (int j = rs + (ngrp << 3); j < re; ++j) {
        uint s = (uint)csr_src[j];
        uint g = xl32[s * 64u + lane];
        const uint4* ep = (const uint4*)(ea_w + (uint)j * 8u);
        uint4 a = ep[0], b = ep[1];
        uint ea[8] = {a.x, a.y, a.z, a.w, b.x, b.y, b.z, b.w};
        float eA = xrA, eB = xrB;
        #pragma unroll
        for (int k = 0; k < 8; ++k) {
            eA = dot2bf(ea[k], wpA[k], eA);
            eB = dot2bf(ea[k], wpB[k], eB);
        }
        edge_core(eA, eB, g);
    }

    // self-loop: (xr + e_mean) = mean of accumulated (xr + e) over edges
    {
        uint g = xl32[(uint)node * 64u + lane];
        float xlA = bf_lo(g), xlB = bf_hi(g);
        float eA, eB;
        if (deg > 0) {
            float inv = 1.f / (float)deg;
            eA = eAs * inv; eB = eBs * inv;
        } else {
            eA = xrA; eB = xrB;
        }
        float sA = eA + xlA;
        float sB = eB + xlB;
        float p = attA6 * sA;
        p = fmaf(attA4, fabsf(sA), p);
        p = fmaf(attB6, sB, p);
        p = fmaf(attB4, fabsf(sB), p);
        p = row16_sum(p);
        float w = exp2f(p);
        d += w;
        accA = fmaf(w, xlA, accA);
        accB = fmaf(w, xlB, accB);
    }

    float invd = 1.f / d;
    float oA = accA * invd + bias[c0];
    float oB = accB * invd + bias[c1];
    float2 xv = *(const float2*)(x + (uint)node * HC + c0);
    float2 o;
    o.x = fmaxf(oA, 0.f) + xv.x;
    o.y = fmaxf(oB, 0.f) + xv.y;
    *(float2*)(out + (uint)node * HC + c0) = o;
}

// ---------------------------------------------------------------------------
extern "C" void kernel_launch(void* const* d_in, const int* in_sizes, int n_in,
                              void* d_out, int out_size, void* d_ws, size_t ws_size,
                              hipStream_t stream)
{
    const float* x         = (const float*)d_in[0];
    const int*   ei        = (const int*)d_in[1];
    const float* edge_attr = (const float*)d_in[2];
    const float* Wl   = (const float*)d_in[5];
    const float* bl   = (const float*)d_in[6];
    const float* Wr   = (const float*)d_in[7];
    const float* br   = (const float*)d_in[8];
    const float* We   = (const float*)d_in[9];
    const float* att  = (const float*)d_in[10];
    const float* bias = (const float*)d_in[11];
    float* out = (float*)d_out;

    const int* src = ei;
    const int* dst = ei + N_EDGES;

    char* p = (char*)d_ws;
    auto alloc = [&](size_t bytes) {
        void* r = (void*)p;
        p += (bytes + 255) & ~(size_t)255;
        return r;
    };
    unsigned short* xlb = (unsigned short*)alloc((size_t)N_NODES * HC * sizeof(unsigned short));
    unsigned short* xrb = (unsigned short*)alloc((size_t)N_NODES * HC * sizeof(unsigned short));
    uint4* xb4      = (uint4*)alloc((size_t)N_NODES * HC * sizeof(unsigned short));
    uint4* wb4      = (uint4*)alloc((size_t)2 * HC * F_IN * sizeof(unsigned short));
    int* deg        = (int*)alloc((size_t)N_NODES * sizeof(int));
    int* row_start  = (int*)alloc((size_t)(N_NODES + 1) * sizeof(int));
    int* cursor     = (int*)alloc((size_t)N_NODES * sizeof(int));
    int* csr_src    = (int*)alloc((size_t)N_EDGES * sizeof(int));
    uint4* csr_ea   = (uint4*)alloc((size_t)N_EDGES * 2 * sizeof(uint4));
    int* bsum       = (int*)alloc(256 * sizeof(int));
    int* boff       = (int*)alloc(256 * sizeof(int));

    hipMemsetAsync(deg, 0, (size_t)N_NODES * sizeof(int), stream);

    cvt_count_kernel<<<N_EDGES / 256, 256, 0, stream>>>(x, Wl, Wr, dst, deg, xb4, wb4);
    proj_mfma_kernel<<<(N_NODES + 63) / 64, 256, 0, stream>>>(xb4, wb4, bl, br, xlb, xrb);
    scan1_kernel<<<NB_SCAN, 1024, 0, stream>>>(deg, row_start, bsum);
    scan2_kernel<<<1, 128, 0, stream>>>(bsum, boff);
    scan3_kernel<<<NB_SCAN, 1024, 0, stream>>>(row_start, boff, cursor);
    scatter_kernel<<<(N_EDGES + 255) / 256, 256, 0, stream>>>(src, dst, edge_attr, cursor, csr_src, csr_ea);
    node_kernel<<<N_NODES, 64, 0, stream>>>(
        x, xlb, xrb, row_start, csr_src, (const uint*)csr_ea, We, att, bias, out);
}